// Round 6
// baseline (244.097 us; speedup 1.0000x reference)
//
#include <hip/hip_runtime.h>

// ---------------------------------------------------------------------------
// YOLO NMS post-processing for MI355X.
// Pipeline: scores (LDS-staged, 2 thr/row) + 32-way sliced histogram ->
// reduce slices -> bucket select -> compact candidates (bucket >= B) ->
// exact rank-by-counting -> scatter by rank (+box decode) -> 64x64 IoU
// bitmask -> batched greedy scan: 64 candidate mask rows per batch staged to
// LDS via global_load_lds DMA (NO dest VGPRs -> allocator cannot spill/
// serialize, unlike register arrays which failed in R3/R5), decide chain on
// LDS with depth-1 prefetch -> gather outputs.
// All IoU-relevant fp32 math uses _rn intrinsics so hipcc's default
// -ffp-contract=fast cannot fuse mul+add into fma (must match numpy fp32).
// ---------------------------------------------------------------------------

#define AS1 __attribute__((address_space(1)))
#define AS3 __attribute__((address_space(3)))

constexpr int    N_ANCH = 100800;
constexpr int    DIMV   = 117;   // 4 box + 1 obj + 80 cls + 32 mask
constexpr int    NCLS   = 80;
constexpr int    TOPKN  = 4096;
constexpr int    MAXDET = 300;
constexpr int    KCAP   = 12288; // candidate capacity
constexpr int    NBUCK  = 16384; // scores < 1.0 -> bits>>16 < 0x3F80 < 16384
constexpr int    NSLICE = 32;

// workspace layout (bytes)
constexpr size_t WS_HIST   = 0;                           // 16384 u32 (final hist)
constexpr size_t WS_SCORES = WS_HIST   + 65536ull * 4;    // 100800 f32
constexpr size_t WS_CLS    = WS_SCORES + 100800ull * 4;   // 100800 i32
constexpr size_t WS_SEL    = WS_CLS    + 100800ull * 4;   // 64 i32: [0]=B [1]=cntAbove [2]=nKeys
constexpr size_t WS_KEYS   = WS_SEL    + 256;             // 12288 u64
constexpr size_t WS_RANK   = WS_KEYS   + (size_t)KCAP * 8;// 12288 i32
constexpr size_t WS_SIDX   = WS_RANK   + (size_t)KCAP * 4;// 4096 i32 (anchor id / sorted slot)
constexpr size_t WS_SSC    = WS_SIDX   + 4096ull * 4;     // 4096 f32 (sorted scores desc)
constexpr size_t WS_BOXES  = WS_SSC    + 4096ull * 4;     // 4096*4 f32 (y1 x1 y2 x2)
constexpr size_t WS_MASK   = WS_BOXES  + 4096ull * 16;    // 4096*64 u64 mask; BEFORE iou_mask
                                                          // runs, the SAME 2 MB holds the
                                                          // 32x16384 u32 hist slices (exact fit)
constexpr size_t WS_OUTI   = WS_MASK   + 4096ull * 64 * 8;// 300 i32
constexpr size_t WS_OUTS   = WS_OUTI   + 1200;            // 300 f32

__global__ void zero_kernel(unsigned* __restrict__ slices, int* __restrict__ sel,
                            int* __restrict__ rank) {
    int i = blockIdx.x * blockDim.x + threadIdx.x;
    if (i < NSLICE * NBUCK) slices[i] = 0u;
    if (i < KCAP)           rank[i]  = 0;
    if (i < 64)             sel[i]   = 0;
}

// 64 rows per 128-thread block, staged to LDS with coalesced float4 loads.
// 2 threads per row: even lane scans classes 0..39, odd lane 40..79, merged
// via shfl_xor. Strict > keeps the first (lowest-class) argmax like numpy.
// Histogram atomics go to slice (blockIdx & 31) to spread hot-line contention.
constexpr int SROWS = 64;
__global__ void score_kernel(const float* __restrict__ x, float* __restrict__ scores,
                             int* __restrict__ cls, unsigned* __restrict__ slices) {
    __shared__ float sx[SROWS * DIMV];           // 29952 B
    int block0 = blockIdx.x * SROWS;
    const float4* src = (const float4*)(x + (size_t)block0 * DIMV); // 64*468 % 16 == 0
    float4* dst = (float4*)sx;
    constexpr int NV4 = SROWS * DIMV / 4;        // 1872
    for (int i = threadIdx.x; i < NV4; i += 128) dst[i] = src[i];
    __syncthreads();
    int row  = threadIdx.x >> 1;
    int half = threadIdx.x & 1;
    const float* rp = sx + row * DIMV;
    float obj = rp[4];
    const float* cp = rp + 5 + half * 40;
    float best = -1.0f;
    int   bc   = half * 40;
#pragma unroll 8
    for (int c = 0; c < 40; ++c) {
        float s = __fmul_rn(cp[c], obj);
        if (s > best) { best = s; bc = half * 40 + c; }
    }
    float so = __shfl_xor(best, 1);
    int   co = __shfl_xor(bc, 1);
    if (half == 0) {
        if (so > best) { best = so; bc = co; }   // strict >: even (lower classes) wins ties
        int a = block0 + row;
        bool valid = obj > 0.25f;
        scores[a] = valid ? best : -1.0f;
        cls[a]    = bc;
        if (valid) {
            unsigned b = __float_as_uint(best) >> 16;   // < 16384 (best in [0,1))
            atomicAdd(&slices[(blockIdx.x & (NSLICE - 1)) * NBUCK + b], 1u);
        }
    }
}

// fold 32 slices into the final histogram. 64 blocks x 256 threads.
__global__ void reduce_hist_kernel(const unsigned* __restrict__ slices,
                                   unsigned* __restrict__ hist) {
    int b = blockIdx.x * 256 + threadIdx.x;
    unsigned s = 0;
#pragma unroll
    for (int k = 0; k < NSLICE; ++k) s += slices[k * NBUCK + b];
    hist[b] = s;
}

// find bucket B: cntAbove(B) < 4096 <= cntAbove(B) + hist[B].
__global__ void select_kernel(const unsigned* __restrict__ hist, int* sel) {
    __shared__ unsigned sv[1024];
    int t = threadIdx.x;
    int base = NBUCK - 16 * (t + 1);          // chunk t covers [base, base+15], t=0 = top
    const uint4* hp = (const uint4*)(hist + base);
    unsigned own = 0;
#pragma unroll
    for (int k = 0; k < 4; ++k) {
        uint4 v = hp[k];
        own += v.x + v.y + v.z + v.w;
    }
    sv[t] = own;
    __syncthreads();
    for (int off = 1; off < 1024; off <<= 1) { // inclusive scan (descending-chunk order)
        unsigned v = (t >= off) ? sv[t - off] : 0u;
        __syncthreads();
        sv[t] += v;
        __syncthreads();
    }
    unsigned incl = sv[t];
    unsigned before = incl - own;
    if (before < (unsigned)TOPKN && incl >= (unsigned)TOPKN) {
        unsigned running = before;
        for (int k = 15; k >= 0; --k) {        // walk buckets descending
            unsigned h = hist[base + k];
            running += h;
            if (running >= (unsigned)TOPKN) {
                sel[0] = base + k;
                sel[1] = (int)(running - h);
                break;
            }
        }
    }
}

// compact all anchors with bucket >= B into keys[]; key = (score_bits<<32)|~a
// -> descending key order == (score desc, idx asc) == stable top_k order.
__global__ void compact_kernel(const float* __restrict__ scores, int* sel,
                               unsigned long long* __restrict__ keys) {
    int a = blockIdx.x * blockDim.x + threadIdx.x;
    if (a >= N_ANCH) return;
    float s = scores[a];
    if (s < 0.0f) return;
    unsigned bits = __float_as_uint(s);
    if ((int)(bits >> 16) < sel[0]) return;
    int pos = atomicAdd(&sel[2], 1);
    if (pos < KCAP) keys[pos] = ((unsigned long long)bits << 32) | (unsigned)(~a);
}

// exact rank by counting: rank[i] = #{j : key_j > key_i}. Keys unique ->
// ranks are a permutation; ranks 0..4095 are the sorted top-4096.
constexpr int NCOLP = 4;
__global__ void rank_kernel(const unsigned long long* __restrict__ keys,
                            const int* __restrict__ sel, int* __restrict__ rank) {
    __shared__ unsigned long long tile[2048];
    int n = sel[2]; if (n > KCAP) n = KCAP;
    int i = blockIdx.x * 256 + threadIdx.x;
    unsigned long long myKey = (i < n) ? keys[i] : 0ull;
    int cnt = 0;
    for (int t0 = blockIdx.y * 2048; t0 < n; t0 += 2048 * NCOLP) {
        int m = n - t0; if (m > 2048) m = 2048;
        for (int j = threadIdx.x; j < m; j += 256) tile[j] = keys[t0 + j];
        __syncthreads();
        int j = 0;
        for (; j + 3 < m; j += 4) {
            cnt += (tile[j]     > myKey);
            cnt += (tile[j + 1] > myKey);
            cnt += (tile[j + 2] > myKey);
            cnt += (tile[j + 3] > myKey);
        }
        for (; j < m; ++j) cnt += (tile[j] > myKey);
        __syncthreads();
    }
    if (i < n && cnt < TOPKN) atomicAdd(&rank[i], cnt);
}

// place keys by rank; also decode the yxyx box for the sorted slot (no fma).
__global__ void scatter_kernel(const float* __restrict__ x,
                               const unsigned long long* __restrict__ keys,
                               const int* __restrict__ sel, const int* __restrict__ rank,
                               int* __restrict__ sidx, float* __restrict__ sscore,
                               float* __restrict__ boxes) {
    int n = sel[2]; if (n > KCAP) n = KCAP;
    int i = blockIdx.x * 256 + threadIdx.x;
    if (i >= n) return;
    int r = rank[i];
    if (r >= TOPKN) return;
    unsigned long long k = keys[i];
    int a = (int)(~(unsigned)(k & 0xFFFFFFFFull));
    sidx[r]   = a;
    sscore[r] = __uint_as_float((unsigned)(k >> 32));
    const float* p = x + (size_t)a * DIMV;
    float xc = p[0], yc = p[1], w = p[2], h = p[3];
    float hw = __fmul_rn(w, 0.5f);
    float hh = __fmul_rn(h, 0.5f);
    boxes[r * 4 + 0] = __fsub_rn(yc, hh);
    boxes[r * 4 + 1] = __fsub_rn(xc, hw);
    boxes[r * 4 + 2] = __fadd_rn(yc, hh);
    boxes[r * 4 + 3] = __fadd_rn(xc, hw);
}

// 64x64 tile IoU bitmask: bit j of mask[r][colT] set iff iou(r, colT*64+j)>0.45 && j_global>r
__global__ void iou_mask_kernel(const float* __restrict__ boxes,
                                unsigned long long* __restrict__ mask) {
    int colT = blockIdx.x, rowT = blockIdx.y;
    int t = threadIdx.x;                 // 0..63
    int r = rowT * 64 + t;
    if (colT < rowT) {                   // whole tile has j < r
        mask[(size_t)r * 64 + colT] = 0ull;
        return;
    }
    __shared__ float cb[64][5];
    int cj = colT * 64 + t;
    {
        float y1 = boxes[cj * 4 + 0], x1 = boxes[cj * 4 + 1];
        float y2 = boxes[cj * 4 + 2], x2 = boxes[cj * 4 + 3];
        cb[t][0] = y1; cb[t][1] = x1; cb[t][2] = y2; cb[t][3] = x2;
        cb[t][4] = __fmul_rn(__fsub_rn(y2, y1), __fsub_rn(x2, x1));
    }
    __syncthreads();
    float ry1 = boxes[r * 4 + 0], rx1 = boxes[r * 4 + 1];
    float ry2 = boxes[r * 4 + 2], rx2 = boxes[r * 4 + 3];
    float rarea = __fmul_rn(__fsub_rn(ry2, ry1), __fsub_rn(rx2, rx1));
    unsigned long long bitsw = 0ull;
#pragma unroll 8
    for (int j = 0; j < 64; ++j) {
        float iy1 = fmaxf(ry1, cb[j][0]);
        float ix1 = fmaxf(rx1, cb[j][1]);
        float iy2 = fminf(ry2, cb[j][2]);
        float ix2 = fminf(rx2, cb[j][3]);
        float ih = fmaxf(__fsub_rn(iy2, iy1), 0.0f);
        float iw = fmaxf(__fsub_rn(ix2, ix1), 0.0f);
        float inter = __fmul_rn(ih, iw);
        float uni = __fsub_rn(__fadd_rn(rarea, cb[j][4]), inter);
        float iou = __fdiv_rn(inter, fmaxf(uni, 1e-9f));
        if (iou > 0.45f && (colT * 64 + j) > r) bitsw |= (1ull << j);
    }
    mask[(size_t)r * 64 + colT] = bitsw;
}

// Batched greedy scan (single wave). lane j owns remv word j.
// Per batch: enumerate next 64 alive rows; DMA their 64 mask rows into LDS
// with global_load_lds (size=16, no dest VGPRs -> nothing to spill; all 32
// issues outstanding, one latency round-trip); decide sequentially on LDS
// with depth-1 prefetch of list[k+1] / tile row k+1. remv only grows, so
// enumerated-alive is a superset of true-alive; stale rows re-checked.
// Early-exit at 300 keeps; padding = lowest-index suppressed rows.
__global__ void __launch_bounds__(64, 1)
nms_scan_kernel(const unsigned long long* __restrict__ mask,
                const float* __restrict__ sscore,
                int* __restrict__ outIdx, float* __restrict__ outScore) {
    constexpr int BATCH = 64;
    int lane = threadIdx.x;              // 64 threads = one wave
    unsigned long long remv = 0ull;
    __shared__ __align__(16) unsigned long long tile[BATCH * 64]; // 32 KB
    __shared__ int list[BATCH];
    __shared__ int keepArr[MAXDET];
    __shared__ unsigned long long remvFinal[64];
    int count = 0;
    int pos = 0;                          // first undecided row
    while (count < MAXDET && pos < TOPKN) {
        // --- enumerate next BATCH alive rows starting at pos (ascending) ---
        unsigned long long avail = ~remv;
        int w0 = pos >> 6;
        if (lane < w0) avail = 0ull;
        else if (lane == w0) avail &= (~0ull) << (pos & 63);
        int cnt = __popcll(avail);
        int pre = cnt;                    // inclusive prefix over lanes
        for (int off = 1; off < 64; off <<= 1) {
            int v = __shfl_up(pre, off);
            if (lane >= off) pre += v;
        }
        int total = __shfl(pre, 63);
        pre -= cnt;                       // exclusive
        unsigned long long a = avail;
        int slot = pre;
        while (a && slot < BATCH) {
            int b = (int)__builtin_ctzll(a);
            a &= a - 1;
            list[slot] = (lane << 6) + b;
            slot++;
        }
        __syncthreads();
        int nb = (total < BATCH) ? total : BATCH;
        if (nb == 0) break;
        int lastRow = list[nb - 1];       // broadcast LDS read (uniform)
        // --- DMA stage nb rows into LDS: issue i covers rows 2i, 2i+1.
        // lane L fetches 16 B at byte (L&31)*16 of row list[2i + (L>>5)];
        // HW writes lane L's data to (uniform LDS base) + L*16.
        int nIss = (nb + 1) >> 1;
        for (int i = 0; i < nIss; ++i) {
            int idx = 2 * i + (lane >> 5);
            if (idx > nb - 1) idx = nb - 1;
            int row = list[idx];
            const char* g = (const char*)(mask + (size_t)row * 64) + (lane & 31) * 16;
            char* l = (char*)(tile + (size_t)i * 128);   // uniform base per issue
            __builtin_amdgcn_global_load_lds((AS1 const unsigned*)g, (AS3 unsigned*)l,
                                             16, 0, 0);
        }
        __syncthreads();                  // drain vmcnt: DMA data visible in LDS
        // --- sequential decide on LDS with depth-1 prefetch ---
        int rcur = list[0];
        unsigned long long mv = tile[lane];
        for (int k = 0; k < nb && count < MAXDET; ++k) {
            int rnext = 0;
            unsigned long long mvnext = 0ull;
            if (k + 1 < nb) {             // issue next ds_reads before the ballot
                rnext  = list[k + 1];
                mvnext = tile[(size_t)(k + 1) * 64 + lane];
            }
            unsigned long long bal = __ballot(((remv >> (rcur & 63)) & 1ull) != 0);
            if (!((bal >> (rcur >> 6)) & 1ull)) {     // still alive -> keep
                if (lane == 0) keepArr[count] = rcur;
                count++;
                remv |= mv;
            }
            rcur = rnext;
            mv   = mvnext;
        }
        pos = lastRow + 1;
        __syncthreads();                  // protect list[]/tile[] reuse
    }
    remvFinal[lane] = remv;
    __syncthreads();
    int K = count;                        // uniform across the wave
    for (int k = lane; k < K; k += 64) {
        int s = keepArr[k];
        outIdx[k] = s;
        outScore[k] = sscore[s];
    }
    if (K < MAXDET && lane == 0) {
        int filled = K;
        for (int w = 0; w < 64 && filled < MAXDET; ++w) {
            unsigned long long word = remvFinal[w];
            while (word && filled < MAXDET) {
                int b = (int)__builtin_ctzll(word);
                word &= word - 1;
                outIdx[filled] = (w << 6) + b;
                outScore[filled] = -1.0f;
                filled++;
            }
        }
    }
}

// emit: boxes[300*4] | classes[300] | scores[300] | masks[300*32]
__global__ void write_out_kernel(const float* __restrict__ x, const int* __restrict__ sidx,
                                 const int* __restrict__ cls, const float* __restrict__ boxes,
                                 const int* __restrict__ outIdx, const float* __restrict__ outScore,
                                 float* __restrict__ out) {
    int o = blockIdx.x;                  // 300
    int t = threadIdx.x;                 // 64
    int s = outIdx[o];
    int a = sidx[s];
    if (t < 32) {
        out[1800 + o * 32 + t] = x[(size_t)a * DIMV + 85 + t];
    } else if (t < 36) {
        out[o * 4 + (t - 32)] = boxes[s * 4 + (t - 32)];
    } else if (t == 36) {
        out[1200 + o] = (float)cls[a];
    } else if (t == 37) {
        out[1500 + o] = outScore[o];
    }
}

extern "C" void kernel_launch(void* const* d_in, const int* in_sizes, int n_in,
                              void* d_out, int out_size, void* d_ws, size_t ws_size,
                              hipStream_t stream) {
    const float* x = (const float*)d_in[0];
    char* ws = (char*)d_ws;
    unsigned*            hist   = (unsigned*)(ws + WS_HIST);
    float*               scores = (float*)(ws + WS_SCORES);
    int*                 cls    = (int*)(ws + WS_CLS);
    int*                 sel    = (int*)(ws + WS_SEL);
    unsigned long long*  keys   = (unsigned long long*)(ws + WS_KEYS);
    int*                 rank   = (int*)(ws + WS_RANK);
    int*                 sidx   = (int*)(ws + WS_SIDX);
    float*               sscore = (float*)(ws + WS_SSC);
    float*               boxes  = (float*)(ws + WS_BOXES);
    unsigned long long*  mask   = (unsigned long long*)(ws + WS_MASK);
    unsigned*            slices = (unsigned*)(ws + WS_MASK);  // overlay: dead before iou_mask
    int*                 outIdx = (int*)(ws + WS_OUTI);
    float*               outSc  = (float*)(ws + WS_OUTS);

    zero_kernel<<<(NSLICE * NBUCK + 255) / 256, 256, 0, stream>>>(slices, sel, rank);
    score_kernel<<<N_ANCH / SROWS, 128, 0, stream>>>(x, scores, cls, slices);
    reduce_hist_kernel<<<NBUCK / 256, 256, 0, stream>>>(slices, hist);
    select_kernel<<<1, 1024, 0, stream>>>(hist, sel);
    compact_kernel<<<(N_ANCH + 255) / 256, 256, 0, stream>>>(scores, sel, keys);
    dim3 rg(KCAP / 256, NCOLP);
    rank_kernel<<<rg, 256, 0, stream>>>(keys, sel, rank);
    scatter_kernel<<<KCAP / 256, 256, 0, stream>>>(x, keys, sel, rank, sidx, sscore, boxes);
    dim3 mg(64, 64);
    iou_mask_kernel<<<mg, 64, 0, stream>>>(boxes, mask);
    nms_scan_kernel<<<1, 64, 0, stream>>>(mask, sscore, outIdx, outSc);
    write_out_kernel<<<MAXDET, 64, 0, stream>>>(x, sidx, cls, boxes, outIdx, outSc, (float*)d_out);
}

// Round 7
// 218.123 us; speedup vs baseline: 1.1191x; 1.1191x over previous
//
#include <hip/hip_runtime.h>

// ---------------------------------------------------------------------------
// YOLO NMS post-processing for MI355X.
// Pipeline: scores (LDS-staged, 2 thr/row) + 32-way sliced histogram ->
// reduce slices -> bucket select -> compact candidates (bucket >= B) ->
// exact rank-by-counting -> scatter by rank (+box decode) -> 64x64 IoU
// bitmask -> word-aligned batched greedy scan: batch w = rows [64w,64w+64) ==
// one remv word == one CONTIGUOUS 32 KB mask block. DMA addresses are pure
// arithmetic (no LDS reads between global_load_lds issues -> compiler cannot
// inject per-issue vmcnt drains, the R6 failure). Double-buffered; dead
// batches skip the sync. Decide walks candidate bits in groups of 8 with
// pipelined ds_reads + ballot recheck -> gather outputs.
// All IoU-relevant fp32 math uses _rn intrinsics so hipcc's default
// -ffp-contract=fast cannot fuse mul+add into fma (must match numpy fp32).
// ---------------------------------------------------------------------------

#define AS1 __attribute__((address_space(1)))
#define AS3 __attribute__((address_space(3)))

constexpr int    N_ANCH = 100800;
constexpr int    DIMV   = 117;   // 4 box + 1 obj + 80 cls + 32 mask
constexpr int    NCLS   = 80;
constexpr int    TOPKN  = 4096;
constexpr int    MAXDET = 300;
constexpr int    KCAP   = 12288; // candidate capacity
constexpr int    NBUCK  = 16384; // scores < 1.0 -> bits>>16 < 0x3F80 < 16384
constexpr int    NSLICE = 32;

// workspace layout (bytes)
constexpr size_t WS_HIST   = 0;                           // 16384 u32 (final hist)
constexpr size_t WS_SCORES = WS_HIST   + 65536ull * 4;    // 100800 f32
constexpr size_t WS_CLS    = WS_SCORES + 100800ull * 4;   // 100800 i32
constexpr size_t WS_SEL    = WS_CLS    + 100800ull * 4;   // 64 i32: [0]=B [1]=cntAbove [2]=nKeys
constexpr size_t WS_KEYS   = WS_SEL    + 256;             // 12288 u64
constexpr size_t WS_RANK   = WS_KEYS   + (size_t)KCAP * 8;// 12288 i32
constexpr size_t WS_SIDX   = WS_RANK   + (size_t)KCAP * 4;// 4096 i32 (anchor id / sorted slot)
constexpr size_t WS_SSC    = WS_SIDX   + 4096ull * 4;     // 4096 f32 (sorted scores desc)
constexpr size_t WS_BOXES  = WS_SSC    + 4096ull * 4;     // 4096*4 f32 (y1 x1 y2 x2)
constexpr size_t WS_MASK   = WS_BOXES  + 4096ull * 16;    // 4096*64 u64 mask; BEFORE iou_mask
                                                          // runs, the SAME 2 MB holds the
                                                          // 32x16384 u32 hist slices (exact fit)
constexpr size_t WS_OUTI   = WS_MASK   + 4096ull * 64 * 8;// 300 i32
constexpr size_t WS_OUTS   = WS_OUTI   + 1200;            // 300 f32

__global__ void zero_kernel(unsigned* __restrict__ slices, int* __restrict__ sel,
                            int* __restrict__ rank) {
    int i = blockIdx.x * blockDim.x + threadIdx.x;
    if (i < NSLICE * NBUCK) slices[i] = 0u;
    if (i < KCAP)           rank[i]  = 0;
    if (i < 64)             sel[i]   = 0;
}

// 64 rows per 128-thread block, staged to LDS with coalesced float4 loads.
// 2 threads per row: even lane scans classes 0..39, odd lane 40..79, merged
// via shfl_xor. Strict > keeps the first (lowest-class) argmax like numpy.
// Histogram atomics go to slice (blockIdx & 31) to spread hot-line contention.
constexpr int SROWS = 64;
__global__ void score_kernel(const float* __restrict__ x, float* __restrict__ scores,
                             int* __restrict__ cls, unsigned* __restrict__ slices) {
    __shared__ float sx[SROWS * DIMV];           // 29952 B
    int block0 = blockIdx.x * SROWS;
    const float4* src = (const float4*)(x + (size_t)block0 * DIMV); // 64*468 % 16 == 0
    float4* dst = (float4*)sx;
    constexpr int NV4 = SROWS * DIMV / 4;        // 1872
    for (int i = threadIdx.x; i < NV4; i += 128) dst[i] = src[i];
    __syncthreads();
    int row  = threadIdx.x >> 1;
    int half = threadIdx.x & 1;
    const float* rp = sx + row * DIMV;
    float obj = rp[4];
    const float* cp = rp + 5 + half * 40;
    float best = -1.0f;
    int   bc   = half * 40;
#pragma unroll 8
    for (int c = 0; c < 40; ++c) {
        float s = __fmul_rn(cp[c], obj);
        if (s > best) { best = s; bc = half * 40 + c; }
    }
    float so = __shfl_xor(best, 1);
    int   co = __shfl_xor(bc, 1);
    if (half == 0) {
        if (so > best) { best = so; bc = co; }   // strict >: even (lower classes) wins ties
        int a = block0 + row;
        bool valid = obj > 0.25f;
        scores[a] = valid ? best : -1.0f;
        cls[a]    = bc;
        if (valid) {
            unsigned b = __float_as_uint(best) >> 16;   // < 16384 (best in [0,1))
            atomicAdd(&slices[(blockIdx.x & (NSLICE - 1)) * NBUCK + b], 1u);
        }
    }
}

// fold 32 slices into the final histogram. 64 blocks x 256 threads.
__global__ void reduce_hist_kernel(const unsigned* __restrict__ slices,
                                   unsigned* __restrict__ hist) {
    int b = blockIdx.x * 256 + threadIdx.x;
    unsigned s = 0;
#pragma unroll
    for (int k = 0; k < NSLICE; ++k) s += slices[k * NBUCK + b];
    hist[b] = s;
}

// find bucket B: cntAbove(B) < 4096 <= cntAbove(B) + hist[B].
__global__ void select_kernel(const unsigned* __restrict__ hist, int* sel) {
    __shared__ unsigned sv[1024];
    int t = threadIdx.x;
    int base = NBUCK - 16 * (t + 1);          // chunk t covers [base, base+15], t=0 = top
    const uint4* hp = (const uint4*)(hist + base);
    unsigned own = 0;
#pragma unroll
    for (int k = 0; k < 4; ++k) {
        uint4 v = hp[k];
        own += v.x + v.y + v.z + v.w;
    }
    sv[t] = own;
    __syncthreads();
    for (int off = 1; off < 1024; off <<= 1) { // inclusive scan (descending-chunk order)
        unsigned v = (t >= off) ? sv[t - off] : 0u;
        __syncthreads();
        sv[t] += v;
        __syncthreads();
    }
    unsigned incl = sv[t];
    unsigned before = incl - own;
    if (before < (unsigned)TOPKN && incl >= (unsigned)TOPKN) {
        unsigned running = before;
        for (int k = 15; k >= 0; --k) {        // walk buckets descending
            unsigned h = hist[base + k];
            running += h;
            if (running >= (unsigned)TOPKN) {
                sel[0] = base + k;
                sel[1] = (int)(running - h);
                break;
            }
        }
    }
}

// compact all anchors with bucket >= B into keys[]; key = (score_bits<<32)|~a
// -> descending key order == (score desc, idx asc) == stable top_k order.
__global__ void compact_kernel(const float* __restrict__ scores, int* sel,
                               unsigned long long* __restrict__ keys) {
    int a = blockIdx.x * blockDim.x + threadIdx.x;
    if (a >= N_ANCH) return;
    float s = scores[a];
    if (s < 0.0f) return;
    unsigned bits = __float_as_uint(s);
    if ((int)(bits >> 16) < sel[0]) return;
    int pos = atomicAdd(&sel[2], 1);
    if (pos < KCAP) keys[pos] = ((unsigned long long)bits << 32) | (unsigned)(~a);
}

// exact rank by counting: rank[i] = #{j : key_j > key_i}. Keys unique ->
// ranks are a permutation; ranks 0..4095 are the sorted top-4096.
constexpr int NCOLP = 4;
__global__ void rank_kernel(const unsigned long long* __restrict__ keys,
                            const int* __restrict__ sel, int* __restrict__ rank) {
    __shared__ unsigned long long tile[2048];
    int n = sel[2]; if (n > KCAP) n = KCAP;
    int i = blockIdx.x * 256 + threadIdx.x;
    unsigned long long myKey = (i < n) ? keys[i] : 0ull;
    int cnt = 0;
    for (int t0 = blockIdx.y * 2048; t0 < n; t0 += 2048 * NCOLP) {
        int m = n - t0; if (m > 2048) m = 2048;
        for (int j = threadIdx.x; j < m; j += 256) tile[j] = keys[t0 + j];
        __syncthreads();
        int j = 0;
        for (; j + 3 < m; j += 4) {
            cnt += (tile[j]     > myKey);
            cnt += (tile[j + 1] > myKey);
            cnt += (tile[j + 2] > myKey);
            cnt += (tile[j + 3] > myKey);
        }
        for (; j < m; ++j) cnt += (tile[j] > myKey);
        __syncthreads();
    }
    if (i < n && cnt < TOPKN) atomicAdd(&rank[i], cnt);
}

// place keys by rank; also decode the yxyx box for the sorted slot (no fma).
__global__ void scatter_kernel(const float* __restrict__ x,
                               const unsigned long long* __restrict__ keys,
                               const int* __restrict__ sel, const int* __restrict__ rank,
                               int* __restrict__ sidx, float* __restrict__ sscore,
                               float* __restrict__ boxes) {
    int n = sel[2]; if (n > KCAP) n = KCAP;
    int i = blockIdx.x * 256 + threadIdx.x;
    if (i >= n) return;
    int r = rank[i];
    if (r >= TOPKN) return;
    unsigned long long k = keys[i];
    int a = (int)(~(unsigned)(k & 0xFFFFFFFFull));
    sidx[r]   = a;
    sscore[r] = __uint_as_float((unsigned)(k >> 32));
    const float* p = x + (size_t)a * DIMV;
    float xc = p[0], yc = p[1], w = p[2], h = p[3];
    float hw = __fmul_rn(w, 0.5f);
    float hh = __fmul_rn(h, 0.5f);
    boxes[r * 4 + 0] = __fsub_rn(yc, hh);
    boxes[r * 4 + 1] = __fsub_rn(xc, hw);
    boxes[r * 4 + 2] = __fadd_rn(yc, hh);
    boxes[r * 4 + 3] = __fadd_rn(xc, hw);
}

// 64x64 tile IoU bitmask: bit j of mask[r][colT] set iff iou(r, colT*64+j)>0.45 && j_global>r
__global__ void iou_mask_kernel(const float* __restrict__ boxes,
                                unsigned long long* __restrict__ mask) {
    int colT = blockIdx.x, rowT = blockIdx.y;
    int t = threadIdx.x;                 // 0..63
    int r = rowT * 64 + t;
    if (colT < rowT) {                   // whole tile has j < r
        mask[(size_t)r * 64 + colT] = 0ull;
        return;
    }
    __shared__ float cb[64][5];
    int cj = colT * 64 + t;
    {
        float y1 = boxes[cj * 4 + 0], x1 = boxes[cj * 4 + 1];
        float y2 = boxes[cj * 4 + 2], x2 = boxes[cj * 4 + 3];
        cb[t][0] = y1; cb[t][1] = x1; cb[t][2] = y2; cb[t][3] = x2;
        cb[t][4] = __fmul_rn(__fsub_rn(y2, y1), __fsub_rn(x2, x1));
    }
    __syncthreads();
    float ry1 = boxes[r * 4 + 0], rx1 = boxes[r * 4 + 1];
    float ry2 = boxes[r * 4 + 2], rx2 = boxes[r * 4 + 3];
    float rarea = __fmul_rn(__fsub_rn(ry2, ry1), __fsub_rn(rx2, rx1));
    unsigned long long bitsw = 0ull;
#pragma unroll 8
    for (int j = 0; j < 64; ++j) {
        float iy1 = fmaxf(ry1, cb[j][0]);
        float ix1 = fmaxf(rx1, cb[j][1]);
        float iy2 = fminf(ry2, cb[j][2]);
        float ix2 = fminf(rx2, cb[j][3]);
        float ih = fmaxf(__fsub_rn(iy2, iy1), 0.0f);
        float iw = fmaxf(__fsub_rn(ix2, ix1), 0.0f);
        float inter = __fmul_rn(ih, iw);
        float uni = __fsub_rn(__fadd_rn(rarea, cb[j][4]), inter);
        float iou = __fdiv_rn(inter, fmaxf(uni, 1e-9f));
        if (iou > 0.45f && (colT * 64 + j) > r) bitsw |= (1ull << j);
    }
    mask[(size_t)r * 64 + colT] = bitsw;
}

// Word-aligned batched greedy scan (single wave). lane j owns remv word j.
// Batch w = rows [64w, 64w+64) = remv word w = contiguous 32 KB of mask[].
// DMA addresses are pure arithmetic -> 32 back-to-back global_load_lds
// issues with NO interleaved LDS reads (no compiler-injected vmcnt drains).
// Iteration w: issue batch w+1 into the other buffer; if batch w has any
// candidate (cand = word w of ~remv, wave-uniform), sync (drain DMA) and
// decide; dead batches skip the sync entirely. Decide: walk cand bits in
// groups of 8 -> 8 pipelined ds_read_b64 + 8 ballot-recheck keeps.
// Early-exit at 300 keeps; padding = lowest-index suppressed rows.
__global__ void __launch_bounds__(64, 1)
nms_scan_kernel(const unsigned long long* __restrict__ mask,
                const float* __restrict__ sscore,
                int* __restrict__ outIdx, float* __restrict__ outScore) {
    int lane = threadIdx.x;              // 64 threads = one wave
    unsigned long long remv = 0ull;
    __shared__ __align__(16) unsigned long long tile[2 * 4096]; // 2 x 32 KB
    __shared__ int keepArr[MAXDET];
    __shared__ unsigned long long remvFinal[64];
    int count = 0;

    // batch w lives in buffer w&1; written at iteration w-1 (or prologue),
    // read at iteration w, overwritten at iteration w+1 (after its read).
    auto issueBatch = [&](int w, int buf) {
        const char* gbase = (const char*)mask + (size_t)w * 32768 + (size_t)lane * 16;
        char* lbase = (char*)tile + (size_t)buf * 32768;
#pragma unroll
        for (int i = 0; i < 32; ++i) {
            __builtin_amdgcn_global_load_lds(
                (AS1 const unsigned*)(gbase + (size_t)i * 1024),
                (AS3 unsigned*)(lbase + (size_t)i * 1024), 16, 0, 0);
        }
    };

    issueBatch(0, 0);
    for (int w = 0; w < 64 && count < MAXDET; ++w) {
        if (w + 1 < 64) issueBatch(w + 1, (w + 1) & 1);
        unsigned long long cand = __shfl(~remv, w);   // wave-uniform
        if (!cand) continue;                          // dead batch: no sync
        __syncthreads();                              // drain DMA queue
        const unsigned long long* trow = tile + (size_t)(w & 1) * 4096;
        while (cand && count < MAXDET) {
            int bs[8];
            unsigned long long c2 = cand;
            int g = 0;
#pragma unroll
            for (int t = 0; t < 8; ++t) {
                bs[t] = c2 ? (int)__builtin_ctzll(c2) : 0;
                if (c2) { c2 &= c2 - 1; g = t + 1; }
            }
            unsigned long long mvs[8];
#pragma unroll
            for (int t = 0; t < 8; ++t) {             // independent, pipelined ds_reads
                mvs[t] = trow[(size_t)bs[t] * 64 + lane];
            }
#pragma unroll
            for (int t = 0; t < 8; ++t) {
                if (t < g && count < MAXDET) {
                    int b = bs[t];
                    unsigned long long bal = __ballot(((remv >> b) & 1ull) != 0);
                    if (!((bal >> w) & 1ull)) {       // still alive -> keep
                        if (lane == 0) keepArr[count] = (w << 6) + b;
                        count++;
                        remv |= mvs[t];
                    }
                }
            }
            cand = c2;
        }
    }
    __syncthreads();                      // drain any outstanding DMA before reuse/exit
    remvFinal[lane] = remv;
    __syncthreads();
    int K = count;                        // uniform across the wave
    for (int k = lane; k < K; k += 64) {
        int s = keepArr[k];
        outIdx[k] = s;
        outScore[k] = sscore[s];
    }
    if (K < MAXDET && lane == 0) {
        int filled = K;
        for (int w = 0; w < 64 && filled < MAXDET; ++w) {
            unsigned long long word = remvFinal[w];
            while (word && filled < MAXDET) {
                int b = (int)__builtin_ctzll(word);
                word &= word - 1;
                outIdx[filled] = (w << 6) + b;
                outScore[filled] = -1.0f;
                filled++;
            }
        }
    }
}

// emit: boxes[300*4] | classes[300] | scores[300] | masks[300*32]
__global__ void write_out_kernel(const float* __restrict__ x, const int* __restrict__ sidx,
                                 const int* __restrict__ cls, const float* __restrict__ boxes,
                                 const int* __restrict__ outIdx, const float* __restrict__ outScore,
                                 float* __restrict__ out) {
    int o = blockIdx.x;                  // 300
    int t = threadIdx.x;                 // 64
    int s = outIdx[o];
    int a = sidx[s];
    if (t < 32) {
        out[1800 + o * 32 + t] = x[(size_t)a * DIMV + 85 + t];
    } else if (t < 36) {
        out[o * 4 + (t - 32)] = boxes[s * 4 + (t - 32)];
    } else if (t == 36) {
        out[1200 + o] = (float)cls[a];
    } else if (t == 37) {
        out[1500 + o] = outScore[o];
    }
}

extern "C" void kernel_launch(void* const* d_in, const int* in_sizes, int n_in,
                              void* d_out, int out_size, void* d_ws, size_t ws_size,
                              hipStream_t stream) {
    const float* x = (const float*)d_in[0];
    char* ws = (char*)d_ws;
    unsigned*            hist   = (unsigned*)(ws + WS_HIST);
    float*               scores = (float*)(ws + WS_SCORES);
    int*                 cls    = (int*)(ws + WS_CLS);
    int*                 sel    = (int*)(ws + WS_SEL);
    unsigned long long*  keys   = (unsigned long long*)(ws + WS_KEYS);
    int*                 rank   = (int*)(ws + WS_RANK);
    int*                 sidx   = (int*)(ws + WS_SIDX);
    float*               sscore = (float*)(ws + WS_SSC);
    float*               boxes  = (float*)(ws + WS_BOXES);
    unsigned long long*  mask   = (unsigned long long*)(ws + WS_MASK);
    unsigned*            slices = (unsigned*)(ws + WS_MASK);  // overlay: dead before iou_mask
    int*                 outIdx = (int*)(ws + WS_OUTI);
    float*               outSc  = (float*)(ws + WS_OUTS);

    zero_kernel<<<(NSLICE * NBUCK + 255) / 256, 256, 0, stream>>>(slices, sel, rank);
    score_kernel<<<N_ANCH / SROWS, 128, 0, stream>>>(x, scores, cls, slices);
    reduce_hist_kernel<<<NBUCK / 256, 256, 0, stream>>>(slices, hist);
    select_kernel<<<1, 1024, 0, stream>>>(hist, sel);
    compact_kernel<<<(N_ANCH + 255) / 256, 256, 0, stream>>>(scores, sel, keys);
    dim3 rg(KCAP / 256, NCOLP);
    rank_kernel<<<rg, 256, 0, stream>>>(keys, sel, rank);
    scatter_kernel<<<KCAP / 256, 256, 0, stream>>>(x, keys, sel, rank, sidx, sscore, boxes);
    dim3 mg(64, 64);
    iou_mask_kernel<<<mg, 64, 0, stream>>>(boxes, mask);
    nms_scan_kernel<<<1, 64, 0, stream>>>(mask, sscore, outIdx, outSc);
    write_out_kernel<<<MAXDET, 64, 0, stream>>>(x, sidx, cls, boxes, outIdx, outSc, (float*)d_out);
}

// Round 8
// 216.910 us; speedup vs baseline: 1.1253x; 1.0056x over previous
//
#include <hip/hip_runtime.h>

// ---------------------------------------------------------------------------
// YOLO NMS post-processing for MI355X.
// Pipeline: scores (LDS-staged, 2 thr/row) + 32-way sliced histogram ->
// reduce slices -> bucket select -> compact candidates (bucket >= B) ->
// exact rank-by-counting -> scatter by rank (+box decode) -> 64x64 IoU
// bitmask -> word-aligned batched greedy scan: batch w = rows [64w,64w+64) ==
// one remv word == one CONTIGUOUS 32 KB mask block, DMA'd to LDS with pure-
// arithmetic addresses. SINGLE WAVE -> no __syncthreads in the loop: batch
// handoff uses raw `s_waitcnt vmcnt(32)` so batch w+1's DMAs stay in flight
// while batch w is decided (R7's barrier drained vmcnt(0) and serialized
// every batch into a full memory round trip). Decide walks candidate bits in
// groups of 8 with pipelined ds_reads + ballot recheck -> gather outputs.
// All IoU-relevant fp32 math uses _rn intrinsics so hipcc's default
// -ffp-contract=fast cannot fuse mul+add into fma (must match numpy fp32).
// ---------------------------------------------------------------------------

#define AS1 __attribute__((address_space(1)))
#define AS3 __attribute__((address_space(3)))

constexpr int    N_ANCH = 100800;
constexpr int    DIMV   = 117;   // 4 box + 1 obj + 80 cls + 32 mask
constexpr int    NCLS   = 80;
constexpr int    TOPKN  = 4096;
constexpr int    MAXDET = 300;
constexpr int    KCAP   = 12288; // candidate capacity
constexpr int    NBUCK  = 16384; // scores < 1.0 -> bits>>16 < 0x3F80 < 16384
constexpr int    NSLICE = 32;

// workspace layout (bytes)
constexpr size_t WS_HIST   = 0;                           // 16384 u32 (final hist)
constexpr size_t WS_SCORES = WS_HIST   + 65536ull * 4;    // 100800 f32
constexpr size_t WS_CLS    = WS_SCORES + 100800ull * 4;   // 100800 i32
constexpr size_t WS_SEL    = WS_CLS    + 100800ull * 4;   // 64 i32: [0]=B [1]=cntAbove [2]=nKeys
constexpr size_t WS_KEYS   = WS_SEL    + 256;             // 12288 u64
constexpr size_t WS_RANK   = WS_KEYS   + (size_t)KCAP * 8;// 12288 i32
constexpr size_t WS_SIDX   = WS_RANK   + (size_t)KCAP * 4;// 4096 i32 (anchor id / sorted slot)
constexpr size_t WS_SSC    = WS_SIDX   + 4096ull * 4;     // 4096 f32 (sorted scores desc)
constexpr size_t WS_BOXES  = WS_SSC    + 4096ull * 4;     // 4096*4 f32 (y1 x1 y2 x2)
constexpr size_t WS_MASK   = WS_BOXES  + 4096ull * 16;    // 4096*64 u64 mask; BEFORE iou_mask
                                                          // runs, the SAME 2 MB holds the
                                                          // 32x16384 u32 hist slices (exact fit)
constexpr size_t WS_OUTI   = WS_MASK   + 4096ull * 64 * 8;// 300 i32
constexpr size_t WS_OUTS   = WS_OUTI   + 1200;            // 300 f32

__global__ void zero_kernel(unsigned* __restrict__ slices, int* __restrict__ sel,
                            int* __restrict__ rank) {
    int i = blockIdx.x * blockDim.x + threadIdx.x;
    if (i < NSLICE * NBUCK) slices[i] = 0u;
    if (i < KCAP)           rank[i]  = 0;
    if (i < 64)             sel[i]   = 0;
}

// 64 rows per 128-thread block, staged to LDS with coalesced float4 loads.
// 2 threads per row: even lane scans classes 0..39, odd lane 40..79, merged
// via shfl_xor. Strict > keeps the first (lowest-class) argmax like numpy.
// Histogram atomics go to slice (blockIdx & 31) to spread hot-line contention.
constexpr int SROWS = 64;
__global__ void score_kernel(const float* __restrict__ x, float* __restrict__ scores,
                             int* __restrict__ cls, unsigned* __restrict__ slices) {
    __shared__ float sx[SROWS * DIMV];           // 29952 B
    int block0 = blockIdx.x * SROWS;
    const float4* src = (const float4*)(x + (size_t)block0 * DIMV); // 64*468 % 16 == 0
    float4* dst = (float4*)sx;
    constexpr int NV4 = SROWS * DIMV / 4;        // 1872
    for (int i = threadIdx.x; i < NV4; i += 128) dst[i] = src[i];
    __syncthreads();
    int row  = threadIdx.x >> 1;
    int half = threadIdx.x & 1;
    const float* rp = sx + row * DIMV;
    float obj = rp[4];
    const float* cp = rp + 5 + half * 40;
    float best = -1.0f;
    int   bc   = half * 40;
#pragma unroll 8
    for (int c = 0; c < 40; ++c) {
        float s = __fmul_rn(cp[c], obj);
        if (s > best) { best = s; bc = half * 40 + c; }
    }
    float so = __shfl_xor(best, 1);
    int   co = __shfl_xor(bc, 1);
    if (half == 0) {
        if (so > best) { best = so; bc = co; }   // strict >: even (lower classes) wins ties
        int a = block0 + row;
        bool valid = obj > 0.25f;
        scores[a] = valid ? best : -1.0f;
        cls[a]    = bc;
        if (valid) {
            unsigned b = __float_as_uint(best) >> 16;   // < 16384 (best in [0,1))
            atomicAdd(&slices[(blockIdx.x & (NSLICE - 1)) * NBUCK + b], 1u);
        }
    }
}

// fold 32 slices into the final histogram. 64 blocks x 256 threads.
__global__ void reduce_hist_kernel(const unsigned* __restrict__ slices,
                                   unsigned* __restrict__ hist) {
    int b = blockIdx.x * 256 + threadIdx.x;
    unsigned s = 0;
#pragma unroll
    for (int k = 0; k < NSLICE; ++k) s += slices[k * NBUCK + b];
    hist[b] = s;
}

// find bucket B: cntAbove(B) < 4096 <= cntAbove(B) + hist[B].
__global__ void select_kernel(const unsigned* __restrict__ hist, int* sel) {
    __shared__ unsigned sv[1024];
    int t = threadIdx.x;
    int base = NBUCK - 16 * (t + 1);          // chunk t covers [base, base+15], t=0 = top
    const uint4* hp = (const uint4*)(hist + base);
    unsigned own = 0;
#pragma unroll
    for (int k = 0; k < 4; ++k) {
        uint4 v = hp[k];
        own += v.x + v.y + v.z + v.w;
    }
    sv[t] = own;
    __syncthreads();
    for (int off = 1; off < 1024; off <<= 1) { // inclusive scan (descending-chunk order)
        unsigned v = (t >= off) ? sv[t - off] : 0u;
        __syncthreads();
        sv[t] += v;
        __syncthreads();
    }
    unsigned incl = sv[t];
    unsigned before = incl - own;
    if (before < (unsigned)TOPKN && incl >= (unsigned)TOPKN) {
        unsigned running = before;
        for (int k = 15; k >= 0; --k) {        // walk buckets descending
            unsigned h = hist[base + k];
            running += h;
            if (running >= (unsigned)TOPKN) {
                sel[0] = base + k;
                sel[1] = (int)(running - h);
                break;
            }
        }
    }
}

// compact all anchors with bucket >= B into keys[]; key = (score_bits<<32)|~a
// -> descending key order == (score desc, idx asc) == stable top_k order.
__global__ void compact_kernel(const float* __restrict__ scores, int* sel,
                               unsigned long long* __restrict__ keys) {
    int a = blockIdx.x * blockDim.x + threadIdx.x;
    if (a >= N_ANCH) return;
    float s = scores[a];
    if (s < 0.0f) return;
    unsigned bits = __float_as_uint(s);
    if ((int)(bits >> 16) < sel[0]) return;
    int pos = atomicAdd(&sel[2], 1);
    if (pos < KCAP) keys[pos] = ((unsigned long long)bits << 32) | (unsigned)(~a);
}

// exact rank by counting: rank[i] = #{j : key_j > key_i}. Keys unique ->
// ranks are a permutation; ranks 0..4095 are the sorted top-4096.
constexpr int NCOLP = 4;
__global__ void rank_kernel(const unsigned long long* __restrict__ keys,
                            const int* __restrict__ sel, int* __restrict__ rank) {
    __shared__ unsigned long long tile[2048];
    int n = sel[2]; if (n > KCAP) n = KCAP;
    int i = blockIdx.x * 256 + threadIdx.x;
    unsigned long long myKey = (i < n) ? keys[i] : 0ull;
    int cnt = 0;
    for (int t0 = blockIdx.y * 2048; t0 < n; t0 += 2048 * NCOLP) {
        int m = n - t0; if (m > 2048) m = 2048;
        for (int j = threadIdx.x; j < m; j += 256) tile[j] = keys[t0 + j];
        __syncthreads();
        int j = 0;
        for (; j + 3 < m; j += 4) {
            cnt += (tile[j]     > myKey);
            cnt += (tile[j + 1] > myKey);
            cnt += (tile[j + 2] > myKey);
            cnt += (tile[j + 3] > myKey);
        }
        for (; j < m; ++j) cnt += (tile[j] > myKey);
        __syncthreads();
    }
    if (i < n && cnt < TOPKN) atomicAdd(&rank[i], cnt);
}

// place keys by rank; also decode the yxyx box for the sorted slot (no fma).
__global__ void scatter_kernel(const float* __restrict__ x,
                               const unsigned long long* __restrict__ keys,
                               const int* __restrict__ sel, const int* __restrict__ rank,
                               int* __restrict__ sidx, float* __restrict__ sscore,
                               float* __restrict__ boxes) {
    int n = sel[2]; if (n > KCAP) n = KCAP;
    int i = blockIdx.x * 256 + threadIdx.x;
    if (i >= n) return;
    int r = rank[i];
    if (r >= TOPKN) return;
    unsigned long long k = keys[i];
    int a = (int)(~(unsigned)(k & 0xFFFFFFFFull));
    sidx[r]   = a;
    sscore[r] = __uint_as_float((unsigned)(k >> 32));
    const float* p = x + (size_t)a * DIMV;
    float xc = p[0], yc = p[1], w = p[2], h = p[3];
    float hw = __fmul_rn(w, 0.5f);
    float hh = __fmul_rn(h, 0.5f);
    boxes[r * 4 + 0] = __fsub_rn(yc, hh);
    boxes[r * 4 + 1] = __fsub_rn(xc, hw);
    boxes[r * 4 + 2] = __fadd_rn(yc, hh);
    boxes[r * 4 + 3] = __fadd_rn(xc, hw);
}

// 64x64 tile IoU bitmask: bit j of mask[r][colT] set iff iou(r, colT*64+j)>0.45 && j_global>r
__global__ void iou_mask_kernel(const float* __restrict__ boxes,
                                unsigned long long* __restrict__ mask) {
    int colT = blockIdx.x, rowT = blockIdx.y;
    int t = threadIdx.x;                 // 0..63
    int r = rowT * 64 + t;
    if (colT < rowT) {                   // whole tile has j < r
        mask[(size_t)r * 64 + colT] = 0ull;
        return;
    }
    __shared__ float cb[64][5];
    int cj = colT * 64 + t;
    {
        float y1 = boxes[cj * 4 + 0], x1 = boxes[cj * 4 + 1];
        float y2 = boxes[cj * 4 + 2], x2 = boxes[cj * 4 + 3];
        cb[t][0] = y1; cb[t][1] = x1; cb[t][2] = y2; cb[t][3] = x2;
        cb[t][4] = __fmul_rn(__fsub_rn(y2, y1), __fsub_rn(x2, x1));
    }
    __syncthreads();
    float ry1 = boxes[r * 4 + 0], rx1 = boxes[r * 4 + 1];
    float ry2 = boxes[r * 4 + 2], rx2 = boxes[r * 4 + 3];
    float rarea = __fmul_rn(__fsub_rn(ry2, ry1), __fsub_rn(rx2, rx1));
    unsigned long long bitsw = 0ull;
#pragma unroll 8
    for (int j = 0; j < 64; ++j) {
        float iy1 = fmaxf(ry1, cb[j][0]);
        float ix1 = fmaxf(rx1, cb[j][1]);
        float iy2 = fminf(ry2, cb[j][2]);
        float ix2 = fminf(rx2, cb[j][3]);
        float ih = fmaxf(__fsub_rn(iy2, iy1), 0.0f);
        float iw = fmaxf(__fsub_rn(ix2, ix1), 0.0f);
        float inter = __fmul_rn(ih, iw);
        float uni = __fsub_rn(__fadd_rn(rarea, cb[j][4]), inter);
        float iou = __fdiv_rn(inter, fmaxf(uni, 1e-9f));
        if (iou > 0.45f && (colT * 64 + j) > r) bitsw |= (1ull << j);
    }
    mask[(size_t)r * 64 + colT] = bitsw;
}

// Word-aligned batched greedy scan (single wave). lane j owns remv word j.
// Batch w = rows [64w, 64w+64) = remv word w = contiguous 32 KB of mask[].
// Single wave -> NO __syncthreads in the loop. Batch handoff is a raw
// `s_waitcnt vmcnt(32)`: after issuing batch w+1 (32 DMAs), waiting until
// <=32 outstanding guarantees batch w has landed while batch w+1 remains in
// flight. Issue order is monotone, so this invariant survives skipped dead
// batches; HW caps outstanding at 63 and self-throttles issue. The only
// vmcnt(0)-style drain is the final __syncthreads before output.
__global__ void __launch_bounds__(64, 1)
nms_scan_kernel(const unsigned long long* __restrict__ mask,
                const float* __restrict__ sscore,
                int* __restrict__ outIdx, float* __restrict__ outScore) {
    int lane = threadIdx.x;              // 64 threads = one wave
    unsigned long long remv = 0ull;
    __shared__ __align__(16) unsigned long long tile[2 * 4096]; // 2 x 32 KB
    __shared__ int keepArr[MAXDET];
    __shared__ unsigned long long remvFinal[64];
    int count = 0;

    // batch w -> buffer w&1; written at iteration w-1 (or prologue), read at
    // iteration w, overwritten at iteration w+1 (strictly after its read).
    auto issueBatch = [&](int w) {
        const char* gbase = (const char*)mask + (size_t)w * 32768 + (size_t)lane * 16;
        char* lbase = (char*)tile + (size_t)(w & 1) * 32768;
#pragma unroll
        for (int i = 0; i < 32; ++i) {
            __builtin_amdgcn_global_load_lds(
                (AS1 const unsigned*)(gbase + (size_t)i * 1024),
                (AS3 unsigned*)(lbase + (size_t)i * 1024), 16, 0, 0);
        }
    };

    issueBatch(0);
    for (int w = 0; w < 64 && count < MAXDET; ++w) {
        if (w + 1 < 64) issueBatch(w + 1);
        unsigned long long cand = __shfl(~remv, w);   // wave-uniform
        if (!cand) continue;                          // dead batch: no wait at all
        // batch w landed once outstanding <= 32 (the last 32 issued = batch w+1)
        asm volatile("s_waitcnt vmcnt(32)" ::: "memory");
        const unsigned long long* trow = tile + (size_t)(w & 1) * 4096;
        while (cand && count < MAXDET) {
            int bs[8];
            unsigned long long c2 = cand;
            int g = 0;
#pragma unroll
            for (int t = 0; t < 8; ++t) {
                bs[t] = c2 ? (int)__builtin_ctzll(c2) : 0;
                if (c2) { c2 &= c2 - 1; g = t + 1; }
            }
            unsigned long long mvs[8];
#pragma unroll
            for (int t = 0; t < 8; ++t) {             // independent, pipelined ds_reads
                mvs[t] = trow[(size_t)bs[t] * 64 + lane];
            }
#pragma unroll
            for (int t = 0; t < 8; ++t) {
                if (t < g && count < MAXDET) {
                    int b = bs[t];
                    unsigned long long bal = __ballot(((remv >> b) & 1ull) != 0);
                    if (!((bal >> w) & 1ull)) {       // still alive -> keep
                        if (lane == 0) keepArr[count] = (w << 6) + b;
                        count++;
                        remv |= mvs[t];
                    }
                }
            }
            cand = c2;
        }
    }
    __syncthreads();                      // drain outstanding DMA before output
    remvFinal[lane] = remv;
    __syncthreads();
    int K = count;                        // uniform across the wave
    for (int k = lane; k < K; k += 64) {
        int s = keepArr[k];
        outIdx[k] = s;
        outScore[k] = sscore[s];
    }
    if (K < MAXDET && lane == 0) {
        int filled = K;
        for (int w = 0; w < 64 && filled < MAXDET; ++w) {
            unsigned long long word = remvFinal[w];
            while (word && filled < MAXDET) {
                int b = (int)__builtin_ctzll(word);
                word &= word - 1;
                outIdx[filled] = (w << 6) + b;
                outScore[filled] = -1.0f;
                filled++;
            }
        }
    }
}

// emit: boxes[300*4] | classes[300] | scores[300] | masks[300*32]
__global__ void write_out_kernel(const float* __restrict__ x, const int* __restrict__ sidx,
                                 const int* __restrict__ cls, const float* __restrict__ boxes,
                                 const int* __restrict__ outIdx, const float* __restrict__ outScore,
                                 float* __restrict__ out) {
    int o = blockIdx.x;                  // 300
    int t = threadIdx.x;                 // 64
    int s = outIdx[o];
    int a = sidx[s];
    if (t < 32) {
        out[1800 + o * 32 + t] = x[(size_t)a * DIMV + 85 + t];
    } else if (t < 36) {
        out[o * 4 + (t - 32)] = boxes[s * 4 + (t - 32)];
    } else if (t == 36) {
        out[1200 + o] = (float)cls[a];
    } else if (t == 37) {
        out[1500 + o] = outScore[o];
    }
}

extern "C" void kernel_launch(void* const* d_in, const int* in_sizes, int n_in,
                              void* d_out, int out_size, void* d_ws, size_t ws_size,
                              hipStream_t stream) {
    const float* x = (const float*)d_in[0];
    char* ws = (char*)d_ws;
    unsigned*            hist   = (unsigned*)(ws + WS_HIST);
    float*               scores = (float*)(ws + WS_SCORES);
    int*                 cls    = (int*)(ws + WS_CLS);
    int*                 sel    = (int*)(ws + WS_SEL);
    unsigned long long*  keys   = (unsigned long long*)(ws + WS_KEYS);
    int*                 rank   = (int*)(ws + WS_RANK);
    int*                 sidx   = (int*)(ws + WS_SIDX);
    float*               sscore = (float*)(ws + WS_SSC);
    float*               boxes  = (float*)(ws + WS_BOXES);
    unsigned long long*  mask   = (unsigned long long*)(ws + WS_MASK);
    unsigned*            slices = (unsigned*)(ws + WS_MASK);  // overlay: dead before iou_mask
    int*                 outIdx = (int*)(ws + WS_OUTI);
    float*               outSc  = (float*)(ws + WS_OUTS);

    zero_kernel<<<(NSLICE * NBUCK + 255) / 256, 256, 0, stream>>>(slices, sel, rank);
    score_kernel<<<N_ANCH / SROWS, 128, 0, stream>>>(x, scores, cls, slices);
    reduce_hist_kernel<<<NBUCK / 256, 256, 0, stream>>>(slices, hist);
    select_kernel<<<1, 1024, 0, stream>>>(hist, sel);
    compact_kernel<<<(N_ANCH + 255) / 256, 256, 0, stream>>>(scores, sel, keys);
    dim3 rg(KCAP / 256, NCOLP);
    rank_kernel<<<rg, 256, 0, stream>>>(keys, sel, rank);
    scatter_kernel<<<KCAP / 256, 256, 0, stream>>>(x, keys, sel, rank, sidx, sscore, boxes);
    dim3 mg(64, 64);
    iou_mask_kernel<<<mg, 64, 0, stream>>>(boxes, mask);
    nms_scan_kernel<<<1, 64, 0, stream>>>(mask, sscore, outIdx, outSc);
    write_out_kernel<<<MAXDET, 64, 0, stream>>>(x, sidx, cls, boxes, outIdx, outSc, (float*)d_out);
}